// Round 4
// baseline (7889.469 us; speedup 1.0000x reference)
//
#include <hip/hip_runtime.h>

typedef unsigned short u16;
typedef unsigned int u32;

#define TS 16
#define BB 64   // batches per block

// ws layout (float offsets): wP2 @0 (65536), wP3 @65536, wP4 @131072 (4096)
// wP2[S*4096 + i*16 + nn] = w2[(S*16+nn)*256 + i]   (S=n>>4, nn=n&15)
// wP4[i*16 + o]           = w4[o*256 + i]

__global__ __launch_bounds__(256) void prep_perm(
    const float* __restrict__ w2, const float* __restrict__ w3,
    const float* __restrict__ w4, float* __restrict__ ws) {
  int e = blockIdx.x * 256 + threadIdx.x;  // grid 256 -> e < 65536
  int S = e >> 12, i = (e >> 4) & 255, nn = e & 15;
  int src = (S * 16 + nn) * 256 + i;
  ws[e] = w2[src];
  ws[65536 + e] = w3[src];
  if (e < 4096) ws[131072 + e] = w4[(e & 15) * 256 + (e >> 4)];
}

// Ascending-i single-accumulator FMA chain for 16 outputs, spikes from bitmask.
// m[8]: 256 spike bits (bit i at dword i>>5, bit i&31). wS: [i][16] weights.
// Adding sf==0 terms is exact (acc+0*w == acc), so the dense chain reproduces
// the reference's ascending-k sequential fp32 rounding bit-for-bit.
__device__ __forceinline__ void chain256x16(const u32 m[8], const float* __restrict__ wS,
                                            float acc[16]) {
#pragma unroll
  for (int nn = 0; nn < 16; ++nn) acc[nn] = 0.f;
#pragma unroll
  for (int d = 0; d < 8; ++d) {
    u32 cur = m[d];
#pragma unroll 1
    for (int c = 0; c < 8; ++c) {
      const float* wrow = wS + (d * 32 + c * 4) * 16;
#pragma unroll
      for (int e = 0; e < 4; ++e) {
        float sf = (float)(cur & 1u);
        cur >>= 1;
#pragma unroll
        for (int nn = 0; nn < 16; ++nn)
          acc[nn] = __fmaf_rn(sf, wrow[e * 16 + nn], acc[nn]);
      }
    }
  }
}

__device__ __forceinline__ void if_update_pack(float vv[16], const float acc[16],
                                               u32& bits) {
  bits = 0;
#pragma unroll
  for (int nn = 0; nn < 16; ++nn) {
    float v = vv[nn] + acc[nn];
    u32 s = (v >= 1.0f) ? 1u : 0u;
    vv[nn] = s ? (v - 1.0f) : v;
    bits |= s << nn;
  }
}

__global__ __launch_bounds__(256, 2) void snn_main(
    const float* __restrict__ x, const float* __restrict__ w1,
    const float* __restrict__ ws, float* __restrict__ out) {
  __shared__ float xsh[BB][16];
  __shared__ u16 smA[BB][16];  // L1 spike bits (n-groups of 16)
  __shared__ u16 smB[BB][16];  // L2 spikes
  __shared__ u16 smC[BB][16];  // L3 spikes

  const int tid = threadIdx.x;
  const int w = tid >> 6;      // wave 0..3
  const int b = tid & 63;      // batch lane
  const int B0 = blockIdx.x * BB;
  const float* wP2 = ws;
  const float* wP3 = ws + 65536;
  const float* wP4 = ws + 131072;

  ((float4*)xsh)[tid] = ((const float4*)(x + B0 * 16))[tid];
  __syncthreads();

  float xr[16];
#pragma unroll
  for (int i = 0; i < 16; ++i) xr[i] = xsh[b][i];

  float v2[4][16], v3[4][16];
#pragma unroll
  for (int q = 0; q < 4; ++q)
#pragma unroll
    for (int nn = 0; nn < 16; ++nn) { v2[q][nn] = 0.f; v3[q][nn] = 0.f; }

#pragma unroll 1
  for (int t = 0; t < TS; ++t) {
    // ---- [A] layer 1: drives + IF re-sim to time t -> smA ----
#pragma unroll 1
    for (int q = 0; q < 4; ++q) {
      const int S = q * 4 + w;
      u32 bits = 0;
#pragma unroll 1
      for (int nn = 0; nn < 16; ++nn) {
        const float* w1r = w1 + (S * 16 + nn) * 16;
        float h = 0.f;
#pragma unroll
        for (int i = 0; i < 16; ++i) h = __fmaf_rn(xr[i], w1r[i], h);
        float v = 0.f;
        u32 sp = 0;
#pragma unroll 1
        for (int tau = 0; tau <= t; ++tau) {
          v += h;
          sp = (v >= 1.0f) ? 1u : 0u;
          v -= sp ? 1.0f : 0.0f;
        }
        bits |= sp << nn;
      }
      smA[b][S] = (u16)bits;
    }
    __syncthreads();

    // ---- [B] layer 2 ----
    u32 m[8];
    {
      uint4 u0 = *(const uint4*)&smA[b][0];
      uint4 u1 = *(const uint4*)&smA[b][8];
      m[0] = u0.x; m[1] = u0.y; m[2] = u0.z; m[3] = u0.w;
      m[4] = u1.x; m[5] = u1.y; m[6] = u1.z; m[7] = u1.w;
    }
    {
      float acc[16]; u32 bits;
      chain256x16(m, wP2 + (0 * 4 + w) * 4096, acc);
      if_update_pack(v2[0], acc, bits); smB[b][0 * 4 + w] = (u16)bits;
      chain256x16(m, wP2 + (1 * 4 + w) * 4096, acc);
      if_update_pack(v2[1], acc, bits); smB[b][1 * 4 + w] = (u16)bits;
      chain256x16(m, wP2 + (2 * 4 + w) * 4096, acc);
      if_update_pack(v2[2], acc, bits); smB[b][2 * 4 + w] = (u16)bits;
      chain256x16(m, wP2 + (3 * 4 + w) * 4096, acc);
      if_update_pack(v2[3], acc, bits); smB[b][3 * 4 + w] = (u16)bits;
    }
    __syncthreads();

    // ---- [C] layer 3 ----
    {
      uint4 u0 = *(const uint4*)&smB[b][0];
      uint4 u1 = *(const uint4*)&smB[b][8];
      m[0] = u0.x; m[1] = u0.y; m[2] = u0.z; m[3] = u0.w;
      m[4] = u1.x; m[5] = u1.y; m[6] = u1.z; m[7] = u1.w;
    }
    {
      float acc[16]; u32 bits;
      chain256x16(m, wP3 + (0 * 4 + w) * 4096, acc);
      if_update_pack(v3[0], acc, bits); smC[b][0 * 4 + w] = (u16)bits;
      chain256x16(m, wP3 + (1 * 4 + w) * 4096, acc);
      if_update_pack(v3[1], acc, bits); smC[b][1 * 4 + w] = (u16)bits;
      chain256x16(m, wP3 + (2 * 4 + w) * 4096, acc);
      if_update_pack(v3[2], acc, bits); smC[b][2 * 4 + w] = (u16)bits;
      chain256x16(m, wP3 + (3 * 4 + w) * 4096, acc);
      if_update_pack(v3[3], acc, bits); smC[b][3 * 4 + w] = (u16)bits;
    }
    __syncthreads();

    // ---- [D] layer 4: 4 outputs per wave (o = w*4+oo), ascending-i chains ----
    {
      uint4 u0 = *(const uint4*)&smC[b][0];
      uint4 u1 = *(const uint4*)&smC[b][8];
      m[0] = u0.x; m[1] = u0.y; m[2] = u0.z; m[3] = u0.w;
      m[4] = u1.x; m[5] = u1.y; m[6] = u1.z; m[7] = u1.w;
      float a4[4] = {0.f, 0.f, 0.f, 0.f};
#pragma unroll
      for (int d = 0; d < 8; ++d) {
        u32 cur = m[d];
#pragma unroll 1
        for (int c = 0; c < 8; ++c) {
          const float* wrow = wP4 + (d * 32 + c * 4) * 16 + w * 4;
#pragma unroll
          for (int e = 0; e < 4; ++e) {
            float sf = (float)(cur & 1u);
            cur >>= 1;
#pragma unroll
            for (int oo = 0; oo < 4; ++oo)
              a4[oo] = __fmaf_rn(sf, wrow[e * 16 + oo], a4[oo]);
          }
        }
      }
      float4 res;
      res.x = a4[0]; res.y = a4[1]; res.z = a4[2]; res.w = a4[3];
      *(float4*)(out + ((size_t)(t * 32768 + B0 + b) * 16 + w * 4)) = res;
    }
    __syncthreads();
  }
}

extern "C" void kernel_launch(void* const* d_in, const int* in_sizes, int n_in,
                              void* d_out, int out_size, void* d_ws, size_t ws_size,
                              hipStream_t stream) {
  const float* x  = (const float*)d_in[0];
  const float* w1 = (const float*)d_in[1];
  const float* w2 = (const float*)d_in[2];
  const float* w3 = (const float*)d_in[3];
  const float* w4 = (const float*)d_in[4];
  float* ws = (float*)d_ws;   // needs 540,672 bytes
  float* out = (float*)d_out;

  hipLaunchKernelGGL(prep_perm, dim3(256), dim3(256), 0, stream, w2, w3, w4, ws);
  hipLaunchKernelGGL(snn_main, dim3(32768 / BB), dim3(256), 0, stream, x, w1, ws, out);
}

// Round 6
// 3223.917 us; speedup vs baseline: 2.4472x; 2.4472x over previous
//
#include <hip/hip_runtime.h>

typedef unsigned short u16;
typedef unsigned int u32;

#define TS 16
#define BB 64   // batches per block

// ws layout (float offsets): wP2 @0 (65536), wP3 @65536, wP4 @131072 (4096)
// wP2[S*4096 + i*16 + nn] = w2[(S*16+nn)*256 + i]   (S=n>>4, nn=n&15)
// wP4[i*16 + o]           = w4[o*256 + i]

__global__ __launch_bounds__(256) void prep_perm(
    const float* __restrict__ w2, const float* __restrict__ w3,
    const float* __restrict__ w4, float* __restrict__ ws) {
  int e = blockIdx.x * 256 + threadIdx.x;  // grid 256 -> e < 65536
  int S = e >> 12, i = (e >> 4) & 255, nn = e & 15;
  int src = (S * 16 + nn) * 256 + i;
  ws[e] = w2[src];
  ws[65536 + e] = w3[src];
  if (e < 4096) ws[131072 + e] = w4[(e & 15) * 256 + (e >> 4)];
}

// Ascending-i single-accumulator FMA chain for 16 outputs, spikes from bitmask.
// m[8]: 256 spike bits (bit i at dword i>>5, bit i&31). wS: [i][16] weights.
// fma(0,w,acc)==acc exactly, so the dense chain reproduces the reference's
// ascending-k sequential fp32 rounding bit-for-bit.
__device__ __forceinline__ void chain256x16(const u32 m[8], const float* __restrict__ wS,
                                            float acc[16]) {
#pragma unroll
  for (int nn = 0; nn < 16; ++nn) acc[nn] = 0.f;
#pragma unroll
  for (int d = 0; d < 8; ++d) {
    u32 cur = m[d];
#pragma unroll 1
    for (int c = 0; c < 8; ++c) {
      const float* wrow = wS + (d * 32 + c * 4) * 16;
#pragma unroll
      for (int e = 0; e < 4; ++e) {
        float sf = (float)(cur & 1u);
        cur >>= 1;
#pragma unroll
        for (int nn = 0; nn < 16; ++nn)
          acc[nn] = __fmaf_rn(sf, wrow[e * 16 + nn], acc[nn]);
      }
    }
  }
}

__device__ __forceinline__ void if_update_pack(float vv[16], const float acc[16],
                                               u32& bits) {
  bits = 0;
#pragma unroll
  for (int nn = 0; nn < 16; ++nn) {
    float v = vv[nn] + acc[nn];
    u32 s = (v >= 1.0f) ? 1u : 0u;
    vv[nn] = s ? (v - 1.0f) : v;
    bits |= s << nn;
  }
}

// 512 threads = 8 waves. Wave w owns S-groups {2w, 2w+1} of each 256-neuron
// layer (weight addresses wave-uniform -> s_load/K$ path) and outputs {2w,2w+1}
// of layer 4. Lane = batch. 16 waves/CU at VGPR<=128.
__global__ __launch_bounds__(512, 4) void snn_main(
    const float* __restrict__ x, const float* __restrict__ w1,
    const float* __restrict__ ws, float* __restrict__ out) {
  __shared__ float xsh[BB][16];
  __shared__ u16 smA[BB][16];  // L1 spike bits (n-groups of 16)
  __shared__ u16 smB[BB][16];  // L2 spikes
  __shared__ u16 smC[BB][16];  // L3 spikes

  const int tid = threadIdx.x;
  const int w = __builtin_amdgcn_readfirstlane(tid >> 6);  // wave 0..7, SGPR
  const int b = tid & 63;      // batch lane
  const int B0 = blockIdx.x * BB;
  const float* wP2 = ws;
  const float* wP3 = ws + 65536;
  const float* wP4 = ws + 131072;

  if (tid < 256) ((float4*)xsh)[tid] = ((const float4*)(x + B0 * 16))[tid];
  __syncthreads();

  float xr[16];
#pragma unroll
  for (int i = 0; i < 16; ++i) xr[i] = xsh[b][i];

  float v2[2][16], v3[2][16];
#pragma unroll
  for (int q = 0; q < 2; ++q)
#pragma unroll
    for (int nn = 0; nn < 16; ++nn) { v2[q][nn] = 0.f; v3[q][nn] = 0.f; }

#pragma unroll 1
  for (int t = 0; t < TS; ++t) {
    // ---- [A] layer 1: drives + IF re-sim to time t -> smA ----
#pragma unroll 1
    for (int q = 0; q < 2; ++q) {
      const int S = w * 2 + q;
      u32 bits = 0;
#pragma unroll 1
      for (int nn = 0; nn < 16; ++nn) {
        const float* w1r = w1 + (S * 16 + nn) * 16;
        float h = 0.f;
#pragma unroll
        for (int i = 0; i < 16; ++i) h = __fmaf_rn(xr[i], w1r[i], h);
        float v = 0.f;
        u32 sp = 0;
#pragma unroll 1
        for (int tau = 0; tau <= t; ++tau) {
          v += h;
          sp = (v >= 1.0f) ? 1u : 0u;
          v -= sp ? 1.0f : 0.0f;
        }
        bits |= sp << nn;
      }
      smA[b][S] = (u16)bits;
    }
    __syncthreads();

    // ---- [B] layer 2 ----
    u32 m[8];
    {
      uint4 u0 = *(const uint4*)&smA[b][0];
      uint4 u1 = *(const uint4*)&smA[b][8];
      m[0] = u0.x; m[1] = u0.y; m[2] = u0.z; m[3] = u0.w;
      m[4] = u1.x; m[5] = u1.y; m[6] = u1.z; m[7] = u1.w;
    }
    {
      float acc[16]; u32 bits;
      chain256x16(m, wP2 + (w * 2 + 0) * 4096, acc);
      if_update_pack(v2[0], acc, bits); smB[b][w * 2 + 0] = (u16)bits;
      chain256x16(m, wP2 + (w * 2 + 1) * 4096, acc);
      if_update_pack(v2[1], acc, bits); smB[b][w * 2 + 1] = (u16)bits;
    }
    __syncthreads();

    // ---- [C] layer 3 ----
    {
      uint4 u0 = *(const uint4*)&smB[b][0];
      uint4 u1 = *(const uint4*)&smB[b][8];
      m[0] = u0.x; m[1] = u0.y; m[2] = u0.z; m[3] = u0.w;
      m[4] = u1.x; m[5] = u1.y; m[6] = u1.z; m[7] = u1.w;
    }
    {
      float acc[16]; u32 bits;
      chain256x16(m, wP3 + (w * 2 + 0) * 4096, acc);
      if_update_pack(v3[0], acc, bits); smC[b][w * 2 + 0] = (u16)bits;
      chain256x16(m, wP3 + (w * 2 + 1) * 4096, acc);
      if_update_pack(v3[1], acc, bits); smC[b][w * 2 + 1] = (u16)bits;
    }
    __syncthreads();

    // ---- [D] layer 4: wave w -> outputs {2w, 2w+1}, ascending-i chains ----
    {
      uint4 u0 = *(const uint4*)&smC[b][0];
      uint4 u1 = *(const uint4*)&smC[b][8];
      m[0] = u0.x; m[1] = u0.y; m[2] = u0.z; m[3] = u0.w;
      m[4] = u1.x; m[5] = u1.y; m[6] = u1.z; m[7] = u1.w;
      float a0 = 0.f, a1 = 0.f;
#pragma unroll
      for (int d = 0; d < 8; ++d) {
        u32 cur = m[d];
#pragma unroll 1
        for (int c = 0; c < 8; ++c) {
          const float* wrow = wP4 + (d * 32 + c * 4) * 16 + w * 2;
#pragma unroll
          for (int e = 0; e < 4; ++e) {
            float sf = (float)(cur & 1u);
            cur >>= 1;
            a0 = __fmaf_rn(sf, wrow[e * 16 + 0], a0);
            a1 = __fmaf_rn(sf, wrow[e * 16 + 1], a1);
          }
        }
      }
      float2 res;
      res.x = a0; res.y = a1;
      *(float2*)(out + ((size_t)(t * 32768 + B0 + b) * 16 + w * 2)) = res;
    }
    __syncthreads();
  }
}

extern "C" void kernel_launch(void* const* d_in, const int* in_sizes, int n_in,
                              void* d_out, int out_size, void* d_ws, size_t ws_size,
                              hipStream_t stream) {
  const float* x  = (const float*)d_in[0];
  const float* w1 = (const float*)d_in[1];
  const float* w2 = (const float*)d_in[2];
  const float* w3 = (const float*)d_in[3];
  const float* w4 = (const float*)d_in[4];
  float* ws = (float*)d_ws;   // needs 540,672 bytes
  float* out = (float*)d_out;

  hipLaunchKernelGGL(prep_perm, dim3(256), dim3(256), 0, stream, w2, w3, w4, ws);
  hipLaunchKernelGGL(snn_main, dim3(32768 / BB), dim3(512), 0, stream, x, w1, ws, out);
}

// Round 7
// 1544.556 us; speedup vs baseline: 5.1079x; 2.0873x over previous
//
#include <hip/hip_runtime.h>

typedef unsigned short u16;
typedef unsigned int u32;

#define TS 16
#define BB 64   // batches per block (lane = batch)

// ws layout (float offsets): wP2 @0 (65536), wP3 @65536, wP4 @131072 (4096)
// wP2[S*4096 + i*16 + nn] = w2[(S*16+nn)*256 + i]   (S = n>>4, nn = n&15)
// wP4[i*16 + o]           = w4[o*256 + i]
__global__ __launch_bounds__(256) void prep_perm(
    const float* __restrict__ w2, const float* __restrict__ w3,
    const float* __restrict__ w4, float* __restrict__ ws) {
  int e = blockIdx.x * 256 + threadIdx.x;  // grid 256 -> e < 65536
  int S = e >> 12, i = (e >> 4) & 255, nn = e & 15;
  int src = (S * 16 + nn) * 256 + i;
  ws[e] = w2[src];
  ws[65536 + e] = w3[src];
  if (e < 4096) ws[131072 + e] = w4[(e & 15) * 256 + (e >> 4)];
}

// Swizzled LDS mask buffer: 64 rows (batch) x 256 u16 (neuron t-masks).
// Row = 512 B = 32 16B-blocks; block i8 of row b lives at b*512 + (i8^(b&31))*16.
// XOR swizzle breaks the 32-way bank conflict of the power-of-2 row stride.
__device__ __forceinline__ u32 lds_off(int b, int i8) {
  return (u32)((b << 9) + (((u32)(i8 ^ (b & 31))) << 4));
}

// One 256->16 layer slice for all 16 timesteps, t-quad accumulators.
// For each (nn, t): acc receives terms i = 0..255 ascending into a single
// fp32 accumulator via __fmaf_rn -> bit-identical to the reference's
// sequential BLAS k-chain (fma(0,w,acc)==acc exactly).
// IF membrane scan runs t-ascending across quads (v carried), identical
// op sequence to the reference: v += h; s = v>=1; v -= s.
__device__ __forceinline__ void layer256(
    const unsigned char* smIn, unsigned char* smOut,
    const float* __restrict__ wS,  // weight slice base for this group
    int b, int g) {
  float v[16];
  u32 pk[8];
#pragma unroll
  for (int nn = 0; nn < 16; ++nn) v[nn] = 0.f;
#pragma unroll
  for (int p = 0; p < 8; ++p) pk[p] = 0u;

#pragma unroll 1
  for (int q = 0; q < 4; ++q) {
    float acc[16][4];
#pragma unroll
    for (int nn = 0; nn < 16; ++nn)
#pragma unroll
      for (int tq = 0; tq < 4; ++tq) acc[nn][tq] = 0.f;
    const int sh = q * 4;
#pragma unroll 1
    for (int i8 = 0; i8 < 32; ++i8) {
      const uint4 mm = *(const uint4*)(smIn + lds_off(b, i8));
      const u32 md[4] = {mm.x, mm.y, mm.z, mm.w};
#pragma unroll
      for (int e = 0; e < 8; ++e) {
        const u32 d = md[e >> 1];
        const u32 mq = ((e & 1) ? (d >> 16) : (d & 0xFFFFu)) >> sh;
        const float* wrow = wS + (i8 * 8 + e) * 16;
        const float sf0 = (float)(mq & 1u);
        const float sf1 = (float)((mq >> 1) & 1u);
        const float sf2 = (float)((mq >> 2) & 1u);
        const float sf3 = (float)((mq >> 3) & 1u);
#pragma unroll
        for (int nn = 0; nn < 16; ++nn) {
          const float wv = wrow[nn];
          acc[nn][0] = __fmaf_rn(sf0, wv, acc[nn][0]);
          acc[nn][1] = __fmaf_rn(sf1, wv, acc[nn][1]);
          acc[nn][2] = __fmaf_rn(sf2, wv, acc[nn][2]);
          acc[nn][3] = __fmaf_rn(sf3, wv, acc[nn][3]);
        }
      }
    }
    // IF scan for t = sh..sh+3 (v carried across quads)
#pragma unroll
    for (int nn = 0; nn < 16; ++nn)
#pragma unroll
      for (int tq = 0; tq < 4; ++tq) {
        float vv = v[nn] + acc[nn][tq];
        u32 s = (vv >= 1.0f) ? 1u : 0u;
        v[nn] = s ? (vv - 1.0f) : vv;
        pk[nn >> 1] |= s << (sh + tq + ((nn & 1) << 4));
      }
  }
  uint4 lo, hi;
  lo.x = pk[0]; lo.y = pk[1]; lo.z = pk[2]; lo.w = pk[3];
  hi.x = pk[4]; hi.y = pk[5]; hi.z = pk[6]; hi.w = pk[7];
  *(uint4*)(smOut + lds_off(b, 2 * g + 0)) = lo;
  *(uint4*)(smOut + lds_off(b, 2 * g + 1)) = hi;
}

// 512 threads = 8 waves, 2 blocks/CU. Wave w owns neuron groups {2w, 2w+1}
// of layers 1-3 and timesteps {2w, 2w+1} of layer 4. Lane = batch.
__global__ __launch_bounds__(512, 4) void snn_main(
    const float* __restrict__ x, const float* __restrict__ w1,
    const float* __restrict__ ws, float* __restrict__ out) {
  __shared__ unsigned char smA[32768];
  __shared__ unsigned char smB[32768];

  const int tid = threadIdx.x;
  const int w = __builtin_amdgcn_readfirstlane(tid >> 6);  // wave 0..7
  const int b = tid & 63;
  const int B0 = blockIdx.x * BB;
  const float* wP2 = ws;
  const float* wP3 = ws + 65536;
  const float* wP4 = ws + 131072;

  // ---- [A] layer 1: drive dot + full 16-step IF -> t-masks in smA ----
  {
    float xr[16];
    const float4* xv = (const float4*)(x + (size_t)(B0 + b) * 16);
#pragma unroll
    for (int qq = 0; qq < 4; ++qq) {
      float4 f4 = xv[qq];
      xr[qq * 4 + 0] = f4.x; xr[qq * 4 + 1] = f4.y;
      xr[qq * 4 + 2] = f4.z; xr[qq * 4 + 3] = f4.w;
    }
#pragma unroll 1
    for (int q2 = 0; q2 < 2; ++q2) {
      const int S = w * 2 + q2;
      u32 pk[8];
#pragma unroll
      for (int p = 0; p < 8; ++p) pk[p] = 0u;
#pragma unroll 1
      for (int nn = 0; nn < 16; ++nn) {
        const float* w1r = w1 + (S * 16 + nn) * 16;
        float h = 0.f;
#pragma unroll
        for (int k = 0; k < 16; ++k) h = __fmaf_rn(xr[k], w1r[k], h);
        float vv = 0.f;
        u32 m = 0;
#pragma unroll
        for (int t = 0; t < TS; ++t) {
          vv += h;
          u32 s = (vv >= 1.0f) ? 1u : 0u;
          vv -= s ? 1.0f : 0.0f;
          m |= s << t;
        }
        pk[nn >> 1] |= m << ((nn & 1) << 4);
      }
      uint4 lo, hi;
      lo.x = pk[0]; lo.y = pk[1]; lo.z = pk[2]; lo.w = pk[3];
      hi.x = pk[4]; hi.y = pk[5]; hi.z = pk[6]; hi.w = pk[7];
      *(uint4*)(smA + lds_off(b, 2 * S + 0)) = lo;
      *(uint4*)(smA + lds_off(b, 2 * S + 1)) = hi;
    }
  }
  __syncthreads();

  // ---- [B] layer 2: smA -> smB ----
  layer256(smA, smB, wP2 + (w * 2 + 0) * 4096, b, w * 2 + 0);
  layer256(smA, smB, wP2 + (w * 2 + 1) * 4096, b, w * 2 + 1);
  __syncthreads();

  // ---- [C] layer 3: smB -> smA ----
  layer256(smB, smA, wP3 + (w * 2 + 0) * 4096, b, w * 2 + 0);
  layer256(smB, smA, wP3 + (w * 2 + 1) * 4096, b, w * 2 + 1);
  __syncthreads();

  // ---- [D] layer 4: wave w -> timesteps {2w, 2w+1}, all 16 outputs ----
#pragma unroll 1
  for (int dt = 0; dt < 2; ++dt) {
    const int t = w * 2 + dt;
    float acc[16];
#pragma unroll
    for (int o = 0; o < 16; ++o) acc[o] = 0.f;
#pragma unroll 1
    for (int i8 = 0; i8 < 32; ++i8) {
      const uint4 mm = *(const uint4*)(smA + lds_off(b, i8));
      const u32 md[4] = {mm.x, mm.y, mm.z, mm.w};
#pragma unroll
      for (int e = 0; e < 8; ++e) {
        const u32 d = md[e >> 1];
        const u32 mask = (e & 1) ? (d >> 16) : (d & 0xFFFFu);
        const float sf = (float)((mask >> t) & 1u);
        const float* wrow = wP4 + (i8 * 8 + e) * 16;
#pragma unroll
        for (int o = 0; o < 16; ++o)
          acc[o] = __fmaf_rn(sf, wrow[o], acc[o]);
      }
    }
    float4* op = (float4*)(out + ((size_t)t * 32768 + B0 + b) * 16);
    float4 r0, r1, r2, r3;
    r0.x = acc[0];  r0.y = acc[1];  r0.z = acc[2];  r0.w = acc[3];
    r1.x = acc[4];  r1.y = acc[5];  r1.z = acc[6];  r1.w = acc[7];
    r2.x = acc[8];  r2.y = acc[9];  r2.z = acc[10]; r2.w = acc[11];
    r3.x = acc[12]; r3.y = acc[13]; r3.z = acc[14]; r3.w = acc[15];
    op[0] = r0; op[1] = r1; op[2] = r2; op[3] = r3;
  }
}

extern "C" void kernel_launch(void* const* d_in, const int* in_sizes, int n_in,
                              void* d_out, int out_size, void* d_ws, size_t ws_size,
                              hipStream_t stream) {
  const float* x  = (const float*)d_in[0];
  const float* w1 = (const float*)d_in[1];
  const float* w2 = (const float*)d_in[2];
  const float* w3 = (const float*)d_in[3];
  const float* w4 = (const float*)d_in[4];
  float* ws = (float*)d_ws;   // needs 540,672 bytes
  float* out = (float*)d_out;

  hipLaunchKernelGGL(prep_perm, dim3(256), dim3(256), 0, stream, w2, w3, w4, ws);
  hipLaunchKernelGGL(snn_main, dim3(32768 / BB), dim3(512), 0, stream, x, w1, ws, out);
}